// Round 18
// baseline (218.992 us; speedup 1.0000x reference)
//
#include <hip/hip_runtime.h>
#include <hip/hip_bf16.h>

// Problem constants (match reference)
#define B_     2
#define CTX_   1024
#define TGT_   256
#define DM_    512
#define L_     1280          // CTX + TGT
#define DI_    1024          // EXPAND * D_MODEL
#define DS_    16            // D_STATE
#define DCONV_ 4
#define NL_    2
#define DTR_   32            // DT_RANK
#define MROWS_ (B_*L_)       // 2560
#define NC_    80            // scan chunks
#define CL_    16            // chunk length (NC_*CL_ == L_)
#define XDBL_N_ (MROWS_*64)  // 163840

typedef unsigned short u16;
typedef __attribute__((ext_vector_type(8))) __bf16 bf16x8;
typedef __attribute__((ext_vector_type(4))) float f32x4;

__device__ __forceinline__ float sigmoidf_(float v){ return 1.f/(1.f+__expf(-v)); }
__device__ __forceinline__ float siluf_(float v){ return v*sigmoidf_(v); }
__device__ __forceinline__ float softplusf_(float v){ return (v>20.f)?v:log1pf(__expf(v)); }
__device__ __forceinline__ u16 f2b(float f){
    union { float f; unsigned u; } x; x.f = f;
    unsigned u = x.u;
    return (u16)((u + 0x7fffu + ((u>>16)&1u)) >> 16);
}
__device__ __forceinline__ float b2f(u16 v){ return __uint_as_float(((unsigned)v)<<16); }
__device__ __forceinline__ void gload_lds16(const void* g, void* l){
    __builtin_amdgcn_global_load_lds((const __attribute__((address_space(1))) unsigned*)g,
                                     (__attribute__((address_space(3))) unsigned*)l, 16, 0, 0);
}
// 2-phase pipeline sync: wait own stage loads, pinned raw barrier
#define PIPE_SYNC do{ asm volatile("s_waitcnt vmcnt(0)" ::: "memory"); \
                      __builtin_amdgcn_sched_barrier(0); \
                      __builtin_amdgcn_s_barrier(); \
                      __builtin_amdgcn_sched_barrier(0); }while(0)

// XCD-aware block swizzle (bijective: nwg % 8 == 0 at every call site)
#define XCD_SWZ(bx, by) \
    int nwg_ = gridDim.x*gridDim.y; \
    int id_  = blockIdx.y*gridDim.x + blockIdx.x; \
    int swz_ = (id_ & 7)*(nwg_>>3) + (id_>>3); \
    int bx = swz_ % gridDim.x, by = swz_ / gridDim.x;

// ---------------- fused init: weight f2b (0..1983) + ctx/tc prelude (1984..3519) + xdbl zero (3520..3839) ----
#define G0_ 262144   // in_w    /8
#define G1_ 131072   // out_w
#define G2_  65536   // pos_w
#define G3_  32768   // outp_w
#define G4_  16384   // xproj_w
__global__ __launch_bounds__(256) void k_init(const float* __restrict__ s0, const float* __restrict__ s1,
                                              const float* __restrict__ s2, const float* __restrict__ s3,
                                              const float* __restrict__ s4,
                                              u16* d0, u16* d1, u16* d2, u16* d3, u16* d4,
                                              const float* __restrict__ ctx, const float* __restrict__ te,
                                              const float* __restrict__ ve, float* __restrict__ x,
                                              u16* __restrict__ xb, u16* __restrict__ tcb,
                                              float* __restrict__ xdbl0, float* __restrict__ xdbl1){
    int blk = blockIdx.x;
    if (blk < 1984){
        int g = blk*256 + threadIdx.x;
        const float* s; u16* d; int base;
        if      (g < G0_)                { s=s0; d=d0; base=g*8; }
        else if (g < G0_+G1_)            { s=s1; d=d1; base=(g-G0_)*8; }
        else if (g < G0_+G1_+G2_)        { s=s2; d=d2; base=(g-G0_-G1_)*8; }
        else if (g < G0_+G1_+G2_+G3_)    { s=s3; d=d3; base=(g-G0_-G1_-G2_)*8; }
        else                             { s=s4; d=d4; base=(g-G0_-G1_-G2_-G3_)*8; }
        float4 a = *(const float4*)&s[base];
        float4 b = *(const float4*)&s[base+4];
        union { u16 us[8]; uint4 v; } o;
        o.us[0]=f2b(a.x); o.us[1]=f2b(a.y); o.us[2]=f2b(a.z); o.us[3]=f2b(a.w);
        o.us[4]=f2b(b.x); o.us[5]=f2b(b.y); o.us[6]=f2b(b.z); o.us[7]=f2b(b.w);
        *(uint4*)&d[base] = o.v;
    } else if (blk < 1984+1024){
        int e = ((blk-1984)*256 + threadIdx.x)*4;   // B*CTX*DM
        int d = e % DM_;
        int l = (e/DM_) % CTX_;
        int b = e/(DM_*CTX_);
        float4 v = *(const float4*)&ctx[e];
        size_t o = ((size_t)(b*L_+l))*DM_ + d;
        *(float4*)&x[o] = v;
        union { u16 us[4]; uint2 q; } p;
        p.us[0]=f2b(v.x); p.us[1]=f2b(v.y); p.us[2]=f2b(v.z); p.us[3]=f2b(v.w);
        *(uint2*)&xb[o] = p.q;
    } else if (blk < 1984+1024+512){
        int e = ((blk-1984-1024)*256 + threadIdx.x)*4; // B*TGT*2DM
        int k = e % (2*DM_);
        int r = e / (2*DM_);
        float4 v = (k < DM_) ? *(const float4*)&te[(size_t)r*DM_ + k]
                             : *(const float4*)&ve[(size_t)r*DM_ + (k-DM_)];
        union { u16 us[4]; uint2 q; } p;
        p.us[0]=f2b(v.x); p.us[1]=f2b(v.y); p.us[2]=f2b(v.z); p.us[3]=f2b(v.w);
        *(uint2*)&tcb[e] = p.q;
    } else if (blk < 3520+160){
        int j = ((blk-3520)*256 + threadIdx.x)*4;     // zero xdbl0
        *(float4*)&xdbl0[j] = make_float4(0.f,0.f,0.f,0.f);
    } else {
        int j = ((blk-3680)*256 + threadIdx.x)*4;     // zero xdbl1
        *(float4*)&xdbl1[j] = make_float4(0.f,0.f,0.f,0.f);
    }
}

// ---------------- bf16 MFMA GEMM, 128x128 tile, BK=64, 8 waves (2x4 of 64x32), 2-phase ----
template<bool WB>
__global__ __launch_bounds__(512) void k_mmx(const u16* __restrict__ A, int lda,
                                             const u16* __restrict__ Bw, int ldb,
                                             float* __restrict__ C, int ldc,
                                             const float* __restrict__ bias, int K,
                                             u16* __restrict__ Cb, int ldcb){
    __shared__ u16 As[2][128*64];
    __shared__ u16 Bs[2][128*64];
    int tid = threadIdx.x;
    int wave = tid >> 6, lane = tid & 63;
    XCD_SWZ(bx, by);
    int bm = by*128, bn = bx*128;
    int wr = (wave>>2)*64, wc = (wave&3)*32;
    f32x4 acc[4][2] = {};
    int lrow = lane & 15, lk = (lane>>4)*8;
    int dphys0 = tid*16;
    int dphys1 = dphys0 + 8192;
    int alog0  = dphys0 ^ (((dphys0>>7)&7)<<4);
    int alog1  = dphys1 ^ (((dphys1>>7)&7)<<4);
    int grow0  = alog0 >> 7,         grow1 = alog1 >> 7;
    int gcol0  = (alog0 & 127) >> 1, gcol1 = (alog1 & 127) >> 1;
    const u16* Ar0 = A  + (size_t)(bm+grow0)*lda + gcol0;
    const u16* Ar1 = A  + (size_t)(bm+grow1)*lda + gcol1;
    const u16* Br0 = Bw + (size_t)(bn+grow0)*ldb + gcol0;
    const u16* Br1 = Bw + (size_t)(bn+grow1)*ldb + gcol1;
    int aoff[4][2], boff[2][2];
    #pragma unroll
    for (int f=0; f<4; ++f){
        int ra = wr + f*16 + lrow;
        #pragma unroll
        for (int s=0;s<2;++s) aoff[f][s] = (ra*128 + s*64 + lk*2) ^ ((ra&7)<<4);
    }
    #pragma unroll
    for (int f=0; f<2; ++f){
        int rb = wc + f*16 + lrow;
        #pragma unroll
        for (int s=0;s<2;++s) boff[f][s] = (rb*128 + s*64 + lk*2) ^ ((rb&7)<<4);
    }
    int nt = K >> 6;
    auto stage = [&](int t, int buf){
        int k0 = t*64;
        gload_lds16(Ar0 + k0, &As[buf][wave*512]);
        gload_lds16(Ar1 + k0, &As[buf][4096 + wave*512]);
        gload_lds16(Br0 + k0, &Bs[buf][wave*512]);
        gload_lds16(Br1 + k0, &Bs[buf][4096 + wave*512]);
    };
    stage(0, 0);
    PIPE_SYNC;
    int cur = 0;
    for (int t=0; t<nt; ++t){
        if (t+1 < nt) stage(t+1, cur^1);
        #pragma unroll
        for (int s=0;s<2;++s){
            bf16x8 af[4], bfr[2];
            #pragma unroll
            for (int f=0; f<4; ++f) af[f]  = *(const bf16x8*)((const char*)As[cur] + aoff[f][s]);
            #pragma unroll
            for (int f=0; f<2; ++f) bfr[f] = *(const bf16x8*)((const char*)Bs[cur] + boff[f][s]);
            #pragma unroll
            for (int fm=0; fm<4; ++fm)
                #pragma unroll
                for (int fn=0; fn<2; ++fn)
                    acc[fm][fn] = __builtin_amdgcn_mfma_f32_16x16x32_bf16(af[fm], bfr[fn], acc[fm][fn], 0,0,0);
        }
        PIPE_SYNC;
        cur ^= 1;
    }
    #pragma unroll
    for (int fm=0; fm<4; ++fm){
        int m0 = bm + wr + fm*16 + (lane>>4)*4;
        #pragma unroll
        for (int fn=0; fn<2; ++fn){
            int n = bn + wc + fn*16 + (lane&15);
            float bsv = (!WB && bias) ? bias[n] : 0.f;
            #pragma unroll
            for (int j=0; j<4; ++j){
                float v = acc[fm][fn][j] + bsv;
                if (WB) Cb[(size_t)(m0+j)*ldcb + n] = f2b(v);
                else    C [(size_t)(m0+j)*ldc  + n] = v;
            }
        }
    }
}

// ---------------- bf16 MFMA GEMM, 64x64 tile, BK=128, 8 waves (2x4 of 32x16), 2-phase ----
// SCAT: remap output rows m(0..511) -> (m>>8)*L_ + CTX_ + (m&255); dual-write fp32 C + bf16 Cb.
template<bool ACC, bool SCAT>
__global__ __launch_bounds__(512) void k_mmx64(const u16* __restrict__ A, int lda,
                                               const u16* __restrict__ Bw, int ldb,
                                               float* __restrict__ C, int ldc,
                                               const float* __restrict__ bias, int ksteps,
                                               u16* __restrict__ Cb, int ldcb){
    __shared__ u16 As[2][64*128];
    __shared__ u16 Bs[2][64*128];
    int tid = threadIdx.x;
    int wave = tid >> 6, lane = tid & 63;
    XCD_SWZ(bx, by);
    int bm = by*64;
    int bn = bx*64;
    int wr = (wave>>2)*32, wc = (wave&3)*16;
    f32x4 acc[2] = {};
    int lrow = lane & 15, lk = (lane>>4)*8;
    int w4 = wave & 3;
    bool isB = wave >= 4;
    const u16* Base = isB ? Bw : A;
    int ldS  = isB ? ldb : lda;
    int brow = isB ? bn : bm;
    const u16* Sr[4];
    int dstoff[4];
    #pragma unroll
    for (int i=0;i<4;++i){
        int dphys = i*4096 + w4*1024 + lane*16;
        int alog  = dphys ^ (((dphys>>8)&7)<<4);
        int grow  = alog >> 8;
        int gcol  = (alog & 255) >> 1;
        Sr[i] = Base + (size_t)(brow+grow)*ldS + gcol;
        dstoff[i] = i*2048 + w4*512;     // u16 units, wave-uniform base
    }
    int aoff[2][4], boff4[4];
    #pragma unroll
    for (int f=0; f<2; ++f){
        int ra = wr + f*16 + lrow;
        #pragma unroll
        for (int s=0;s<4;++s) aoff[f][s] = (ra*256 + s*64 + lk*2) ^ ((ra&7)<<4);
    }
    { int rb = wc + lrow;
      #pragma unroll
      for (int s=0;s<4;++s) boff4[s] = (rb*256 + s*64 + lk*2) ^ ((rb&7)<<4); }
    auto stage = [&](int t, int buf){
        int k0 = t*128;
        u16* dstbuf = isB ? &Bs[buf][0] : &As[buf][0];
        #pragma unroll
        for (int i=0;i<4;++i) gload_lds16(Sr[i] + k0, dstbuf + dstoff[i]);
    };
    stage(0, 0);
    PIPE_SYNC;
    int cur = 0;
    for (int t = 0; t < ksteps; ++t){
        if (t+1 < ksteps) stage(t+1, cur^1);
        #pragma unroll
        for (int s=0;s<4;++s){
            bf16x8 af[2], bfr;
            #pragma unroll
            for (int f=0; f<2; ++f) af[f] = *(const bf16x8*)((const char*)As[cur] + aoff[f][s]);
            bfr = *(const bf16x8*)((const char*)Bs[cur] + boff4[s]);
            #pragma unroll
            for (int fm=0; fm<2; ++fm)
                acc[fm] = __builtin_amdgcn_mfma_f32_16x16x32_bf16(af[fm], bfr, acc[fm], 0,0,0);
        }
        PIPE_SYNC;
        cur ^= 1;
    }
    #pragma unroll
    for (int fm=0; fm<2; ++fm){
        int m0 = bm + wr + fm*16 + (lane>>4)*4;
        int n = bn + wc + (lane&15);
        float bsv = bias ? bias[n] : 0.f;
        #pragma unroll
        for (int j=0; j<4; ++j){
            float v = acc[fm][j] + bsv;
            int m = m0 + j;
            if (SCAT){
                int xrow = (m>>8)*L_ + CTX_ + (m&255);
                C [(size_t)xrow*ldc  + n] = v;
                Cb[(size_t)xrow*ldcb + n] = f2b(v);
            } else {
                size_t off = (size_t)m*ldc + n;
                if (ACC) v += C[off];
                C[off] = v;
                if (Cb) Cb[(size_t)m*ldcb + n] = f2b(v);
            }
        }
    }
}

// ---------------- xproj GEMM with FUSED depthwise conv+silu on A; atomic accumulate to xdbl ----
__global__ __launch_bounds__(512) void k_xproj(const u16* __restrict__ xzb, const u16* __restrict__ Bw,
                                               float* __restrict__ C, const float* __restrict__ cw,
                                               const float* __restrict__ cb){
    __shared__ u16 As[64*32];
    __shared__ u16 Bs[64*32];
    __shared__ u16 sXC[67*32];
    int tid = threadIdx.x;
    int wave = tid >> 6, lane = tid & 63;
    XCD_SWZ(bx, by);
    int bm = by*64;
    int kbase = bx*128;                    // 4 ksteps of 32
    int b0row = (bm/L_)*L_;
    int wr = (wave>>2)*32, wc = (wave&3)*16;
    f32x4 acc[2] = {};
    int lrow = lane & 15, lk = (lane>>4)*8;
    int w4 = wave & 3;
    int dphys = w4*1024 + lane*16;
    int alog  = dphys ^ (((dphys>>7)&7)<<4);
    int grow  = alog >> 6;
    int gcol  = (alog & 63) >> 1;
    const u16* Br = Bw + (size_t)grow*DI_ + gcol;    // N=64 rows, bn=0
    int aoff[2], boff;
    #pragma unroll
    for (int f=0; f<2; ++f){
        int ra = wr + f*16 + lrow;
        aoff[f] = (ra*64 + lk*2) ^ (((ra>>1)&7)<<4);
    }
    { int rb = wc + lrow; boff = (rb*64 + lk*2) ^ (((rb>>1)&7)<<4); }
    for (int t = 0; t < 4; ++t){
        int k0 = kbase + t*32;
        if (wave >= 4) gload_lds16(Br + k0, &Bs[w4*512]);
        if (tid < 268){
            int rr = tid >> 2, c16 = (tid & 3)*8;
            int gr = bm + rr - 3;
            uint4 v = make_uint4(0,0,0,0);
            if (gr >= b0row) v = *(const uint4*)&xzb[(size_t)gr*2048 + k0 + c16];
            *(uint4*)&sXC[rr*32 + c16] = v;
        }
        __syncthreads();
        {
            int o = tid*4, rr = o >> 5, cc0 = o & 31;
            union { u16 us[4]; uint2 q; } w;
            #pragma unroll
            for (int j=0;j<4;++j){
                int cc = cc0 + j, d = k0 + cc;
                float4 wv = *(const float4*)&cw[d*4];
                float a = cb[d];
                a = fmaf(b2f(sXC[(rr+0)*32+cc]), wv.x, a);
                a = fmaf(b2f(sXC[(rr+1)*32+cc]), wv.y, a);
                a = fmaf(b2f(sXC[(rr+2)*32+cc]), wv.z, a);
                a = fmaf(b2f(sXC[(rr+3)*32+cc]), wv.w, a);
                w.us[j] = f2b(siluf_(a));
            }
            int L0 = rr*64 + cc0*2;
            int ph = L0 ^ (((L0>>7)&7)<<4);
            *(uint2*)((char*)As + ph) = w.q;
        }
        __syncthreads();
        bf16x8 af[2], bfr;
        #pragma unroll
        for (int f=0; f<2; ++f) af[f] = *(const bf16x8*)((const char*)As + aoff[f]);
        bfr = *(const bf16x8*)((const char*)Bs + boff);
        #pragma unroll
        for (int fm=0; fm<2; ++fm)
            acc[fm] = __builtin_amdgcn_mfma_f32_16x16x32_bf16(af[fm], bfr, acc[fm], 0,0,0);
        __syncthreads();
    }
    // atomic accumulate partial tile directly into xdbl (zeroed by k_init)
    #pragma unroll
    for (int fm=0; fm<2; ++fm){
        int m0 = bm + wr + fm*16 + (lane>>4)*4;
        int n = wc + (lane&15);
        #pragma unroll
        for (int j=0; j<4; ++j)
            atomicAdd(&C[(size_t)(m0+j)*64 + n], acc[fm][j]);
    }
}

// ---------------- chunked selective scan (CL=16), Δ-proj + conv fused; bf16 chunk state ----
__global__ __launch_bounds__(256) void k_scan1(const u16* __restrict__ xzb, const float* __restrict__ xdbl,
                                               const float* __restrict__ dtw, const float* __restrict__ dtb,
                                               const float* __restrict__ cw, const float* __restrict__ cb,
                                               const float* __restrict__ Alog,
                                               u16* __restrict__ hend, u16* __restrict__ P){
    __shared__ float sX[CL_*64];      // [16][64]: dt 0:32 | B 32:48 | C 48:64
    __shared__ float sW[64*33];
    __shared__ float sDtb[64];
    __shared__ float sDel[CL_*64];
    __shared__ float sU[CL_*64];
    __shared__ u16   sXC[19*64];
    int blk = blockIdx.x;             // B*NC*16 = 2560
    int dgrp = blk & 15;
    int c = (blk>>4) % NC_;
    int b = blk/(16*NC_);
    int d0 = dgrp*64;
    int tid = threadIdx.x;
    size_t rowbase = (size_t)(b*L_ + c*CL_);
    {
        int e = tid*4;
        *(float4*)&sX[e] = *(const float4*)&xdbl[rowbase*64 + e];
        int w0 = tid*8, dr = w0>>5, kk = w0&31;
        float4 wa = *(const float4*)&dtw[(size_t)(d0+dr)*DTR_ + kk];
        float4 wb = *(const float4*)&dtw[(size_t)(d0+dr)*DTR_ + kk + 4];
        sW[dr*33+kk+0]=wa.x; sW[dr*33+kk+1]=wa.y; sW[dr*33+kk+2]=wa.z; sW[dr*33+kk+3]=wa.w;
        sW[dr*33+kk+4]=wb.x; sW[dr*33+kk+5]=wb.y; sW[dr*33+kk+6]=wb.z; sW[dr*33+kk+7]=wb.w;
        if (tid < 64) sDtb[tid] = dtb[d0+tid];
    }
    if (tid < 152){                    // 19 rows x 8 uint4
        int rr = tid >> 3, c8 = (tid & 7)*8;
        long gr = (long)rowbase + rr - 3;
        uint4 v = make_uint4(0,0,0,0);
        if (gr >= (long)b*L_) v = *(const uint4*)&xzb[(size_t)gr*2048 + d0 + c8];
        *(uint4*)&sXC[rr*64 + c8] = v;
    }
    __syncthreads();
    {
        int o = tid*4, t = o>>6, dd0 = o&63;
        #pragma unroll
        for (int j=0;j<4;++j){
            int dd = dd0 + j, d = d0 + dd;
            float4 wv = *(const float4*)&cw[d*4];
            float a = cb[d];
            a = fmaf(b2f(sXC[(t+0)*64+dd]), wv.x, a);
            a = fmaf(b2f(sXC[(t+1)*64+dd]), wv.y, a);
            a = fmaf(b2f(sXC[(t+2)*64+dd]), wv.z, a);
            a = fmaf(b2f(sXC[(t+3)*64+dd]), wv.w, a);
            sU[t*64+dd] = siluf_(a);
        }
    }
    // Δ-projection, register-tiled: thread owns dd, 4 t's; w cached in 16-wide halves
    {
        int dd = tid & 63, t0 = (tid>>6)*4;
        float accv[4];
        float db = sDtb[dd];
        #pragma unroll
        for (int j=0;j<4;++j) accv[j] = db;
        #pragma unroll
        for (int kk=0; kk<DTR_; kk+=16){
            float w[16];
            #pragma unroll
            for (int k=0;k<16;++k) w[k] = sW[dd*33+kk+k];
            #pragma unroll
            for (int j=0;j<4;++j){
                int t = t0 + j;
                #pragma unroll
                for (int k=0;k<16;++k) accv[j] = fmaf(sX[t*64+kk+k], w[k], accv[j]);
            }
        }
        #pragma unroll
        for (int j=0;j<4;++j) sDel[(t0+j)*64+dd] = softplusf_(accv[j]);
    }
    __syncthreads();
    int dl = tid>>2, sg = (tid&3)*4;
    int d = d0 + dl;
    float A[4];
    #pragma unroll
    for (int i=0;i<4;++i) A[i] = -__expf(Alog[d*DS_ + sg + i]);
    float h[4] = {0,0,0,0}, Pl[4] = {1.f,1.f,1.f,1.f};
    #pragma unroll
    for (int t=0;t<CL_;++t){
        float delta = sDel[t*64+dl];
        float du    = delta*sU[t*64+dl];
        #pragma unroll
        for (int i=0;i<4;++i){
            float a = __expf(delta*A[i]);
            h[i]  = fmaf(a, h[i], du*sX[t*64 + 32 + sg + i]);
            Pl[i] *= a;
        }
    }
    size_t ob = ((size_t)((b*NC_+c)*DI_) + d)*DS_ + sg;   // multiple of 4 -> uint2 aligned
    union { u16 us[4]; uint2 q; } oh, op;
    #pragma unroll
    for (int i=0;i<4;++i){ oh.us[i]=f2b(h[i]); op.us[i]=f2b(Pl[i]); }
    *(uint2*)&hend[ob] = oh.q;
    *(uint2*)&P[ob]    = op.q;
}

// pass 2: sequential combine across chunks (8-deep load pipelining); hstart in-place into hend (bf16)
__global__ __launch_bounds__(256) void k_scan2(u16* __restrict__ hend, const u16* __restrict__ P){
    int g = blockIdx.x*256 + threadIdx.x;        // B*DI*DS = 32768
    int s = g & 15;
    int d = (g>>4) & 1023;
    int b = g>>14;
    size_t base = ((size_t)b*NC_*DI_ + d)*DS_ + s;
    const size_t cs = (size_t)DI_*DS_;
    float h = 0.f;
    for (int c0=0;c0<NC_;c0+=8){
        float he[8], p[8];
        #pragma unroll
        for (int j=0;j<8;++j){ size_t idx = base + (size_t)(c0+j)*cs; he[j]=b2f(hend[idx]); p[j]=b2f(P[idx]); }
        #pragma unroll
        for (int j=0;j<8;++j){ size_t idx = base + (size_t)(c0+j)*cs; hend[idx]=f2b(h); h=fmaf(p[j],h,he[j]); }
    }
}

// pass 3: rerun chunk with correct initial state; conv + Δ fused; gate; emit bf16 y
__global__ __launch_bounds__(256) void k_scan3(const u16* __restrict__ xzb, const float* __restrict__ xdbl,
                                               const float* __restrict__ dtw, const float* __restrict__ dtb,
                                               const float* __restrict__ cw, const float* __restrict__ cb,
                                               const float* __restrict__ Alog, const float* __restrict__ Dsk,
                                               const u16* __restrict__ hstart, u16* __restrict__ yb){
    __shared__ float sX[CL_*64];
    __shared__ float sW[64*33];
    __shared__ float sDtb[64];
    __shared__ float sDel[CL_*64];
    __shared__ float sU[CL_*64];
    __shared__ float sY[CL_*64];
    __shared__ u16   sXC[19*64];
    int blk = blockIdx.x;
    int dgrp = blk & 15;
    int c = (blk>>4) % NC_;
    int b = blk/(16*NC_);
    int d0 = dgrp*64;
    int tid = threadIdx.x;
    size_t rowbase = (size_t)(b*L_ + c*CL_);
    {
        int e = tid*4;
        *(float4*)&sX[e] = *(const float4*)&xdbl[rowbase*64 + e];
        int w0 = tid*8, dr = w0>>5, kk = w0&31;
        float4 wa = *(const float4*)&dtw[(size_t)(d0+dr)*DTR_ + kk];
        float4 wb = *(const float4*)&dtw[(size_t)(d0+dr)*DTR_ + kk + 4];
        sW[dr*33+kk+0]=wa.x; sW[dr*33+kk+1]=wa.y; sW[dr*33+kk+2]=wa.z; sW[dr*33+kk+3]=wa.w;
        sW[dr*33+kk+4]=wb.x; sW[dr*33+kk+5]=wb.y; sW[dr*33+kk+6]=wb.z; sW[dr*33+kk+7]=wb.w;
        if (tid < 64) sDtb[tid] = dtb[d0+tid];
    }
    if (tid < 152){
        int rr = tid >> 3, c8 = (tid & 7)*8;
        long gr = (long)rowbase + rr - 3;
        uint4 v = make_uint4(0,0,0,0);
        if (gr >= (long)b*L_) v = *(const uint4*)&xzb[(size_t)gr*2048 + d0 + c8];
        *(uint4*)&sXC[rr*64 + c8] = v;
    }
    __syncthreads();
    {
        int o = tid*4, t = o>>6, dd0 = o&63;
        #pragma unroll
        for (int j=0;j<4;++j){
            int dd = dd0 + j, d = d0 + dd;
            float4 wv = *(const float4*)&cw[d*4];
            float a = cb[d];
            a = fmaf(b2f(sXC[(t+0)*64+dd]), wv.x, a);
            a = fmaf(b2f(sXC[(t+1)*64+dd]), wv.y, a);
            a = fmaf(b2f(sXC[(t+2)*64+dd]), wv.z, a);
            a = fmaf(b2f(sXC[(t+3)*64+dd]), wv.w, a);
            sU[t*64+dd] = siluf_(a);
        }
    }
    // Δ-projection, register-tiled (identical arithmetic order to baseline)
    {
        int dd = tid & 63, t0 = (tid>>6)*4;
        float accv[4];
        float db = sDtb[dd];
        #pragma unroll
        for (int j=0;j<4;++j) accv[j] = db;
        #pragma unroll
        for (int kk=0; kk<DTR_; kk+=16){
            float w[16];
            #pragma unroll
            for (int k=0;k<16;++k) w[k] = sW[dd*33+kk+k];
            #pragma unroll
            for (int j=0;j<4;++j){
                int t = t0 + j;
                #pragma unroll
                for (int k=0;k<16;++k) accv[j] = fmaf(sX[t*64+kk+k], w[k], accv[j]);
            }
        }
        #pragma unroll
        for (int j=0;j<4;++j) sDel[(t0+j)*64+dd] = softplusf_(accv[j]);
    }
    __syncthreads();
    int dl = tid>>2, sg = (tid&3)*4;
    int d = d0 + dl;
    float A[4];
    #pragma unroll
    for (int i=0;i<4;++i) A[i] = -__expf(Alog[d*DS_ + sg + i]);
    size_t ib = ((size_t)((b*NC_+c)*DI_) + d)*DS_ + sg;
    uint2 hq = *(const uint2*)&hstart[ib];
    float h[4] = { b2f((u16)(hq.x&0xffffu)), b2f((u16)(hq.x>>16)),
                   b2f((u16)(hq.y&0xffffu)), b2f((u16)(hq.y>>16)) };
    #pragma unroll
    for (int t=0;t<CL_;++t){
        float delta = sDel[t*64+dl];
        float du    = delta*sU[t*64+dl];
        float yt = 0.f;
        #pragma unroll
        for (int i=0;i<4;++i){
            float a = __expf(delta*A[i]);
            h[i] = fmaf(a, h[i], du*sX[t*64 + 32 + sg + i]);
            yt   = fmaf(h[i], sX[t*64 + 48 + sg + i], yt);
        }
        yt += __shfl_xor(yt, 1);
        yt += __shfl_xor(yt, 2);
        if ((tid&3)==0) sY[t*64+dl] = yt;
    }
    __syncthreads();
    {
        int e = tid*4, st = e>>6, dd = e&63;
        size_t off = (rowbase+st)*DI_ + d0 + dd;
        float4 dskv = *(const float4*)&Dsk[d0+dd];
        uint2 zz = *(const uint2*)&xzb[(rowbase+st)*2048 + DI_ + d0 + dd];
        float z0 = __uint_as_float(zz.x<<16),  z1 = __uint_as_float(zz.x & 0xffff0000u);
        float z2 = __uint_as_float(zz.y<<16),  z3 = __uint_as_float(zz.y & 0xffff0000u);
        union { u16 us[4]; uint2 q; } o;
        o.us[0] = f2b((sY[e+0] + sU[e+0]*dskv.x) * siluf_(z0));
        o.us[1] = f2b((sY[e+1] + sU[e+1]*dskv.y) * siluf_(z1));
        o.us[2] = f2b((sY[e+2] + sU[e+2]*dskv.z) * siluf_(z2));
        o.us[3] = f2b((sY[e+3] + sU[e+3]*dskv.w) * siluf_(z3));
        *(uint2*)&yb[off] = o.q;
    }
}

// ---------------- fused LayerNorm + final projection (BK=128 GEMM phase) ----------------
__global__ __launch_bounds__(512) void k_lnmm(const float* __restrict__ x, const float* __restrict__ g_,
                                              const float* __restrict__ be_,
                                              const u16* __restrict__ Bw,
                                              const float* __restrict__ bias, float* __restrict__ out){
    __shared__ u16 ALn[64*512];       // 64 KB
    __shared__ u16 Bs[2][64*128];     // 2 x 16 KB
    int tid = threadIdx.x;
    int wave = tid >> 6, lane = tid & 63;
    int bm = blockIdx.y*64, bn = blockIdx.x*64;
    for (int rr8 = 0; rr8 < 8; ++rr8){
        int rr = wave*8 + rr8;
        int tr = bm + rr;
        int xrow = (tr>>8)*L_ + CTX_ + (tr&255);
        const float* row = x + (size_t)xrow*DM_ + lane*8;
        float4 a = *(const float4*)row;
        float4 b = *(const float4*)(row+4);
        float s  = a.x+a.y+a.z+a.w + b.x+b.y+b.z+b.w;
        float sq = a.x*a.x+a.y*a.y+a.z*a.z+a.w*a.w + b.x*b.x+b.y*b.y+b.z*b.z+b.w*b.w;
        #pragma unroll
        for (int off=32; off; off>>=1){ s += __shfl_xor(s,off); sq += __shfl_xor(sq,off); }
        float mu = s*(1.f/DM_);
        float rs = rsqrtf(sq*(1.f/DM_) - mu*mu + 1e-5f);
        int c0 = lane*8;
        float4 g0 = *(const float4*)&g_[c0],  g1 = *(const float4*)&g_[c0+4];
        float4 b0 = *(const float4*)&be_[c0], b1 = *(const float4*)&be_[c0+4];
        union { u16 us[8]; uint4 v; } o;
        o.us[0]=f2b((a.x-mu)*rs*g0.x+b0.x); o.us[1]=f2b((a.y-mu)*rs*g0.y+b0.y);
        o.us[2]=f2b((a.z-mu)*rs*g0.z+b0.z); o.us[3]=f2b((a.w-mu)*rs*g0.w+b0.w);
        o.us[4]=f2b((b.x-mu)*rs*g1.x+b1.x); o.us[5]=f2b((b.y-mu)*rs*g1.y+b1.y);
        o.us[6]=f2b((b.z-mu)*rs*g1.z+b1.z); o.us[7]=f2b((b.w-mu)*rs*g1.w+b1.w);
        int ph = (rr*1024) + ((lane*16) ^ ((rr&7)<<4));
        *(uint4*)((char*)ALn + ph) = o.v;
    }
    __syncthreads();
    int wr = (wave>>2)*32, wc = (wave&3)*16;
    f32x4 acc[2] = {};
    int lrow = lane & 15, lk = (lane>>4)*8;
    int w4 = wave & 3;
    const u16* Sr[4];
    int dstoff[4];
    #pragma unroll
    for (int i=0;i<4;++i){
        int dphys = i*4096 + w4*1024 + lane*16;
        int alog  = dphys ^ (((dphys>>8)&7)<<4);
        int grow  = alog >> 8;
        int gcol  = (alog & 255) >> 1;
        Sr[i] = Bw + (size_t)(bn+grow)*DM_ + gcol;
        dstoff[i] = i*2048 + w4*512;
    }
    int boff4[4];
    { int rb = wc + lrow;
      #pragma unroll
      for (int s=0;s<4;++s) boff4[s] = (rb*256 + s*64 + lk*2) ^ ((rb&7)<<4); }
    int ra0 = wr + lrow, ra1 = wr + 16 + lrow;
    auto stage = [&](int t, int buf){
        if (wave >= 4){
            int k0 = t*128;
            #pragma unroll
            for (int i=0;i<4;++i) gload_lds16(Sr[i] + k0, &Bs[buf][0] + dstoff[i]);
        }
    };
    stage(0, 0);
    PIPE_SYNC;
    int cur = 0;
    for (int t = 0; t < 4; ++t){      // K=512 / 128
        if (t+1 < 4) stage(t+1, cur^1);
        #pragma unroll
        for (int s=0;s<4;++s){
            int kb = (t*128 + s*32 + lk)*2;
            bf16x8 af0 = *(const bf16x8*)((const char*)ALn + (ra0*1024 + (kb ^ ((ra0&7)<<4))));
            bf16x8 af1 = *(const bf16x8*)((const char*)ALn + (ra1*1024 + (kb ^ ((ra1&7)<<4))));
            bf16x8 bfr = *(const bf16x8*)((const char*)Bs[cur] + boff4[s]);
            acc[0] = __builtin_amdgcn_mfma_f32_16x16x32_bf16(af0, bfr, acc[0], 0,0,0);
            acc[1] = __builtin_amdgcn_mfma_f32_16x16x32_bf16(af1, bfr, acc[1], 0,0,0);
        }
        PIPE_SYNC;
        cur ^= 1;
    }
    #pragma unroll
    for (int fm=0; fm<2; ++fm){
        int m0 = bm + wr + fm*16 + (lane>>4)*4;
        int n = bn + wc + (lane&15);
        float bsv = bias[n];
        #pragma unroll
        for (int j=0; j<4; ++j)
            out[(size_t)(m0+j)*DM_ + n] = acc[fm][j] + bsv;
    }
}

// ---------------- host launch ----------------
extern "C" void kernel_launch(void* const* d_in, const int* in_sizes, int n_in,
                              void* d_out, int out_size, void* d_ws, size_t ws_size,
                              hipStream_t stream) {
    const float* ctx    = (const float*)d_in[0];
    const float* te     = (const float*)d_in[1];
    const float* ve     = (const float*)d_in[2];
    const float* pos_w  = (const float*)d_in[4];
    const float* pos_b  = (const float*)d_in[5];
    const float* outp_w = (const float*)d_in[6];
    const float* outp_b = (const float*)d_in[7];
    const float* ln_g   = (const float*)d_in[8];
    const float* ln_b   = (const float*)d_in[9];
    const float* in_w   = (const float*)d_in[10];
    const float* conv_w = (const float*)d_in[11];
    const float* conv_b = (const float*)d_in[12];
    const float* xproj_w= (const float*)d_in[13];
    const float* dt_w   = (const float*)d_in[14];
    const float* dt_b   = (const float*)d_in[15];
    const float* A_log  = (const float*)d_in[16];
    const float* D_skip = (const float*)d_in[17];
    const float* out_w  = (const float*)d_in[18];
    float* out = (float*)d_out;

    float* ws    = (float*)d_ws;
    float* x     = ws;                       // 1,310,720 fp32
    float* xdbl0 = x     + 1310720;          //   163,840 fp32
    float* xdbl1 = xdbl0 + 163840;           //   163,840 fp32
    u16*  hend  = (u16*)(xdbl1 + 163840);    // 2,621,440 u16 (bf16)
    u16*  P     = hend  + 2621440;           // 2,621,440
    u16*  xb    = P     + 2621440;           // 1,310,720
    u16*  tcb   = xb    + 1310720;           //   524,288
    u16*  yb    = tcb   + 524288;            // 2,621,440
    u16*  xzb   = yb    + 2621440;           // 5,242,880
    u16*  inwb  = xzb   + 5242880;           // 2,097,152
    u16*  outwb = inwb  + 2097152;           // 1,048,576
    u16*  poswb = outwb + 1048576;           //   524,288
    u16*  outpwb= poswb + 524288;            //   262,144
    u16*  xpwb  = outpwb+ 262144;            //   131,072

    k_init<<<3840, 256, 0, stream>>>(in_w, out_w, pos_w, outp_w, xproj_w,
                                     inwb, outwb, poswb, outpwb, xpwb,
                                     ctx, te, ve, x, xb, tcb, xdbl0, xdbl1);
    // pos projection, scattered directly into x/xb target rows (K=1024 -> 8 BK128 steps)
    k_mmx64<false,true><<<dim3(8,8), 512, 0, stream>>>(tcb, 2*DM_, poswb, 2*DM_, x, DM_, pos_b, 8, xb, DM_);

    for (int i=0;i<NL_;++i){
        const u16*   inwbi  = inwb + (size_t)i*2*DI_*DM_;
        const float* cw     = conv_w  + (size_t)i*DI_*DCONV_;
        const float* cb     = conv_b  + (size_t)i*DI_;
        const u16*   xpwbi  = xpwb + (size_t)i*(DTR_+2*DS_)*DI_;
        const float* dtw    = dt_w    + (size_t)i*DI_*DTR_;
        const float* dtb    = dt_b    + (size_t)i*DI_;
        const float* Ai     = A_log   + (size_t)i*DI_*DS_;
        const float* Dsk    = D_skip  + (size_t)i*DI_;
        const u16*   outwbi = outwb + (size_t)i*DM_*DI_;
        float*       xdbl   = (i == 0) ? xdbl0 : xdbl1;

        k_mmx<true><<<dim3(16,20), 512, 0, stream>>>(xb, DM_, inwbi, DM_, nullptr, 0, nullptr, DM_, xzb, 2*DI_);
        k_xproj<<<dim3(8,40), 512, 0, stream>>>(xzb, xpwbi, xdbl, cw, cb);
        k_scan1<<<2560, 256, 0, stream>>>(xzb, xdbl, dtw, dtb, cw, cb, Ai, hend, P);
        k_scan2<<<128, 256, 0, stream>>>(hend, P);
        k_scan3<<<2560, 256, 0, stream>>>(xzb, xdbl, dtw, dtb, cw, cb, Ai, Dsk, hend, yb);
        // out-proj: K=1024 -> 8 BK128 steps
        k_mmx64<true,false><<<dim3(8,40), 512, 0, stream>>>(yb, DI_, outwbi, DI_, x, DM_, nullptr, 8, xb, DM_);
    }

    k_lnmm<<<dim3(8,8), 512, 0, stream>>>(x, ln_g, ln_b, outpwb, outp_b, out);
}

// Round 19
// 207.964 us; speedup vs baseline: 1.0530x; 1.0530x over previous
//
#include <hip/hip_runtime.h>
#include <hip/hip_bf16.h>

// Problem constants (match reference)
#define B_     2
#define CTX_   1024
#define TGT_   256
#define DM_    512
#define L_     1280          // CTX + TGT
#define DI_    1024          // EXPAND * D_MODEL
#define DS_    16            // D_STATE
#define DCONV_ 4
#define NL_    2
#define DTR_   32            // DT_RANK
#define MROWS_ (B_*L_)       // 2560
#define NC_    80            // scan chunks
#define CL_    16            // chunk length (NC_*CL_ == L_)
#define XDBL_N_ (MROWS_*64)  // 163840

typedef unsigned short u16;
typedef __attribute__((ext_vector_type(8))) __bf16 bf16x8;
typedef __attribute__((ext_vector_type(4))) float f32x4;

__device__ __forceinline__ float sigmoidf_(float v){ return 1.f/(1.f+__expf(-v)); }
__device__ __forceinline__ float siluf_(float v){ return v*sigmoidf_(v); }
__device__ __forceinline__ float softplusf_(float v){ return (v>20.f)?v:log1pf(__expf(v)); }
__device__ __forceinline__ u16 f2b(float f){
    union { float f; unsigned u; } x; x.f = f;
    unsigned u = x.u;
    return (u16)((u + 0x7fffu + ((u>>16)&1u)) >> 16);
}
__device__ __forceinline__ float b2f(u16 v){ return __uint_as_float(((unsigned)v)<<16); }
__device__ __forceinline__ void gload_lds16(const void* g, void* l){
    __builtin_amdgcn_global_load_lds((const __attribute__((address_space(1))) unsigned*)g,
                                     (__attribute__((address_space(3))) unsigned*)l, 16, 0, 0);
}
// 2-phase pipeline sync: wait own stage loads, pinned raw barrier
#define PIPE_SYNC do{ asm volatile("s_waitcnt vmcnt(0)" ::: "memory"); \
                      __builtin_amdgcn_sched_barrier(0); \
                      __builtin_amdgcn_s_barrier(); \
                      __builtin_amdgcn_sched_barrier(0); }while(0)

// XCD-aware block swizzle (bijective: nwg % 8 == 0 at every call site)
#define XCD_SWZ(bx, by) \
    int nwg_ = gridDim.x*gridDim.y; \
    int id_  = blockIdx.y*gridDim.x + blockIdx.x; \
    int swz_ = (id_ & 7)*(nwg_>>3) + (id_>>3); \
    int bx = swz_ % gridDim.x, by = swz_ / gridDim.x;

// ---------------- fused init: weight f2b (0..1983) + ctx/tc prelude (1984..3519) + xdbl zero (3520..3839) ----
#define G0_ 262144   // in_w    /8
#define G1_ 131072   // out_w
#define G2_  65536   // pos_w
#define G3_  32768   // outp_w
#define G4_  16384   // xproj_w
__global__ __launch_bounds__(256) void k_init(const float* __restrict__ s0, const float* __restrict__ s1,
                                              const float* __restrict__ s2, const float* __restrict__ s3,
                                              const float* __restrict__ s4,
                                              u16* d0, u16* d1, u16* d2, u16* d3, u16* d4,
                                              const float* __restrict__ ctx, const float* __restrict__ te,
                                              const float* __restrict__ ve, float* __restrict__ x,
                                              u16* __restrict__ xb, u16* __restrict__ tcb,
                                              float* __restrict__ xdbl0, float* __restrict__ xdbl1){
    int blk = blockIdx.x;
    if (blk < 1984){
        int g = blk*256 + threadIdx.x;
        const float* s; u16* d; int base;
        if      (g < G0_)                { s=s0; d=d0; base=g*8; }
        else if (g < G0_+G1_)            { s=s1; d=d1; base=(g-G0_)*8; }
        else if (g < G0_+G1_+G2_)        { s=s2; d=d2; base=(g-G0_-G1_)*8; }
        else if (g < G0_+G1_+G2_+G3_)    { s=s3; d=d3; base=(g-G0_-G1_-G2_)*8; }
        else                             { s=s4; d=d4; base=(g-G0_-G1_-G2_-G3_)*8; }
        float4 a = *(const float4*)&s[base];
        float4 b = *(const float4*)&s[base+4];
        union { u16 us[8]; uint4 v; } o;
        o.us[0]=f2b(a.x); o.us[1]=f2b(a.y); o.us[2]=f2b(a.z); o.us[3]=f2b(a.w);
        o.us[4]=f2b(b.x); o.us[5]=f2b(b.y); o.us[6]=f2b(b.z); o.us[7]=f2b(b.w);
        *(uint4*)&d[base] = o.v;
    } else if (blk < 1984+1024){
        int e = ((blk-1984)*256 + threadIdx.x)*4;   // B*CTX*DM
        int d = e % DM_;
        int l = (e/DM_) % CTX_;
        int b = e/(DM_*CTX_);
        float4 v = *(const float4*)&ctx[e];
        size_t o = ((size_t)(b*L_+l))*DM_ + d;
        *(float4*)&x[o] = v;
        union { u16 us[4]; uint2 q; } p;
        p.us[0]=f2b(v.x); p.us[1]=f2b(v.y); p.us[2]=f2b(v.z); p.us[3]=f2b(v.w);
        *(uint2*)&xb[o] = p.q;
    } else if (blk < 1984+1024+512){
        int e = ((blk-1984-1024)*256 + threadIdx.x)*4; // B*TGT*2DM
        int k = e % (2*DM_);
        int r = e / (2*DM_);
        float4 v = (k < DM_) ? *(const float4*)&te[(size_t)r*DM_ + k]
                             : *(const float4*)&ve[(size_t)r*DM_ + (k-DM_)];
        union { u16 us[4]; uint2 q; } p;
        p.us[0]=f2b(v.x); p.us[1]=f2b(v.y); p.us[2]=f2b(v.z); p.us[3]=f2b(v.w);
        *(uint2*)&tcb[e] = p.q;
    } else if (blk < 3520+160){
        int j = ((blk-3520)*256 + threadIdx.x)*4;     // zero xdbl0
        *(float4*)&xdbl0[j] = make_float4(0.f,0.f,0.f,0.f);
    } else {
        int j = ((blk-3680)*256 + threadIdx.x)*4;     // zero xdbl1
        *(float4*)&xdbl1[j] = make_float4(0.f,0.f,0.f,0.f);
    }
}

// ---------------- bf16 MFMA GEMM, 128x128 tile, BK=64, 8 waves (2x4 of 64x32), 2-phase ----
template<bool WB>
__global__ __launch_bounds__(512) void k_mmx(const u16* __restrict__ A, int lda,
                                             const u16* __restrict__ Bw, int ldb,
                                             float* __restrict__ C, int ldc,
                                             const float* __restrict__ bias, int K,
                                             u16* __restrict__ Cb, int ldcb){
    __shared__ u16 As[2][128*64];
    __shared__ u16 Bs[2][128*64];
    int tid = threadIdx.x;
    int wave = tid >> 6, lane = tid & 63;
    XCD_SWZ(bx, by);
    int bm = by*128, bn = bx*128;
    int wr = (wave>>2)*64, wc = (wave&3)*32;
    f32x4 acc[4][2] = {};
    int lrow = lane & 15, lk = (lane>>4)*8;
    int dphys0 = tid*16;
    int dphys1 = dphys0 + 8192;
    int alog0  = dphys0 ^ (((dphys0>>7)&7)<<4);
    int alog1  = dphys1 ^ (((dphys1>>7)&7)<<4);
    int grow0  = alog0 >> 7,         grow1 = alog1 >> 7;
    int gcol0  = (alog0 & 127) >> 1, gcol1 = (alog1 & 127) >> 1;
    const u16* Ar0 = A  + (size_t)(bm+grow0)*lda + gcol0;
    const u16* Ar1 = A  + (size_t)(bm+grow1)*lda + gcol1;
    const u16* Br0 = Bw + (size_t)(bn+grow0)*ldb + gcol0;
    const u16* Br1 = Bw + (size_t)(bn+grow1)*ldb + gcol1;
    int aoff[4][2], boff[2][2];
    #pragma unroll
    for (int f=0; f<4; ++f){
        int ra = wr + f*16 + lrow;
        #pragma unroll
        for (int s=0;s<2;++s) aoff[f][s] = (ra*128 + s*64 + lk*2) ^ ((ra&7)<<4);
    }
    #pragma unroll
    for (int f=0; f<2; ++f){
        int rb = wc + f*16 + lrow;
        #pragma unroll
        for (int s=0;s<2;++s) boff[f][s] = (rb*128 + s*64 + lk*2) ^ ((rb&7)<<4);
    }
    int nt = K >> 6;
    auto stage = [&](int t, int buf){
        int k0 = t*64;
        gload_lds16(Ar0 + k0, &As[buf][wave*512]);
        gload_lds16(Ar1 + k0, &As[buf][4096 + wave*512]);
        gload_lds16(Br0 + k0, &Bs[buf][wave*512]);
        gload_lds16(Br1 + k0, &Bs[buf][4096 + wave*512]);
    };
    stage(0, 0);
    PIPE_SYNC;
    int cur = 0;
    for (int t=0; t<nt; ++t){
        if (t+1 < nt) stage(t+1, cur^1);
        #pragma unroll
        for (int s=0;s<2;++s){
            bf16x8 af[4], bfr[2];
            #pragma unroll
            for (int f=0; f<4; ++f) af[f]  = *(const bf16x8*)((const char*)As[cur] + aoff[f][s]);
            #pragma unroll
            for (int f=0; f<2; ++f) bfr[f] = *(const bf16x8*)((const char*)Bs[cur] + boff[f][s]);
            #pragma unroll
            for (int fm=0; fm<4; ++fm)
                #pragma unroll
                for (int fn=0; fn<2; ++fn)
                    acc[fm][fn] = __builtin_amdgcn_mfma_f32_16x16x32_bf16(af[fm], bfr[fn], acc[fm][fn], 0,0,0);
        }
        PIPE_SYNC;
        cur ^= 1;
    }
    #pragma unroll
    for (int fm=0; fm<4; ++fm){
        int m0 = bm + wr + fm*16 + (lane>>4)*4;
        #pragma unroll
        for (int fn=0; fn<2; ++fn){
            int n = bn + wc + fn*16 + (lane&15);
            float bsv = (!WB && bias) ? bias[n] : 0.f;
            #pragma unroll
            for (int j=0; j<4; ++j){
                float v = acc[fm][fn][j] + bsv;
                if (WB) Cb[(size_t)(m0+j)*ldcb + n] = f2b(v);
                else    C [(size_t)(m0+j)*ldc  + n] = v;
            }
        }
    }
}

// ---------------- bf16 MFMA GEMM, 64x64 tile, BK=128, 8 waves (2x4 of 32x16), 2-phase ----
// SCAT: remap output rows m(0..511) -> (m>>8)*L_ + CTX_ + (m&255); dual-write fp32 C + bf16 Cb.
template<bool ACC, bool SCAT>
__global__ __launch_bounds__(512) void k_mmx64(const u16* __restrict__ A, int lda,
                                               const u16* __restrict__ Bw, int ldb,
                                               float* __restrict__ C, int ldc,
                                               const float* __restrict__ bias, int ksteps,
                                               u16* __restrict__ Cb, int ldcb){
    __shared__ u16 As[2][64*128];
    __shared__ u16 Bs[2][64*128];
    int tid = threadIdx.x;
    int wave = tid >> 6, lane = tid & 63;
    XCD_SWZ(bx, by);
    int bm = by*64;
    int bn = bx*64;
    int wr = (wave>>2)*32, wc = (wave&3)*16;
    f32x4 acc[2] = {};
    int lrow = lane & 15, lk = (lane>>4)*8;
    int w4 = wave & 3;
    bool isB = wave >= 4;
    const u16* Base = isB ? Bw : A;
    int ldS  = isB ? ldb : lda;
    int brow = isB ? bn : bm;
    const u16* Sr[4];
    int dstoff[4];
    #pragma unroll
    for (int i=0;i<4;++i){
        int dphys = i*4096 + w4*1024 + lane*16;
        int alog  = dphys ^ (((dphys>>8)&7)<<4);
        int grow  = alog >> 8;
        int gcol  = (alog & 255) >> 1;
        Sr[i] = Base + (size_t)(brow+grow)*ldS + gcol;
        dstoff[i] = i*2048 + w4*512;     // u16 units, wave-uniform base
    }
    int aoff[2][4], boff4[4];
    #pragma unroll
    for (int f=0; f<2; ++f){
        int ra = wr + f*16 + lrow;
        #pragma unroll
        for (int s=0;s<4;++s) aoff[f][s] = (ra*256 + s*64 + lk*2) ^ ((ra&7)<<4);
    }
    { int rb = wc + lrow;
      #pragma unroll
      for (int s=0;s<4;++s) boff4[s] = (rb*256 + s*64 + lk*2) ^ ((rb&7)<<4); }
    auto stage = [&](int t, int buf){
        int k0 = t*128;
        u16* dstbuf = isB ? &Bs[buf][0] : &As[buf][0];
        #pragma unroll
        for (int i=0;i<4;++i) gload_lds16(Sr[i] + k0, dstbuf + dstoff[i]);
    };
    stage(0, 0);
    PIPE_SYNC;
    int cur = 0;
    for (int t = 0; t < ksteps; ++t){
        if (t+1 < ksteps) stage(t+1, cur^1);
        #pragma unroll
        for (int s=0;s<4;++s){
            bf16x8 af[2], bfr;
            #pragma unroll
            for (int f=0; f<2; ++f) af[f] = *(const bf16x8*)((const char*)As[cur] + aoff[f][s]);
            bfr = *(const bf16x8*)((const char*)Bs[cur] + boff4[s]);
            #pragma unroll
            for (int fm=0; fm<2; ++fm)
                acc[fm] = __builtin_amdgcn_mfma_f32_16x16x32_bf16(af[fm], bfr, acc[fm], 0,0,0);
        }
        PIPE_SYNC;
        cur ^= 1;
    }
    #pragma unroll
    for (int fm=0; fm<2; ++fm){
        int m0 = bm + wr + fm*16 + (lane>>4)*4;
        int n = bn + wc + (lane&15);
        float bsv = bias ? bias[n] : 0.f;
        #pragma unroll
        for (int j=0; j<4; ++j){
            float v = acc[fm][j] + bsv;
            int m = m0 + j;
            if (SCAT){
                int xrow = (m>>8)*L_ + CTX_ + (m&255);
                C [(size_t)xrow*ldc  + n] = v;
                Cb[(size_t)xrow*ldcb + n] = f2b(v);
            } else {
                size_t off = (size_t)m*ldc + n;
                if (ACC) v += C[off];
                C[off] = v;
                if (Cb) Cb[(size_t)m*ldcb + n] = f2b(v);
            }
        }
    }
}

// ---------------- xproj GEMM with FUSED depthwise conv+silu on A; atomic accumulate to xdbl ----
__global__ __launch_bounds__(512) void k_xproj(const u16* __restrict__ xzb, const u16* __restrict__ Bw,
                                               float* __restrict__ C, const float* __restrict__ cw,
                                               const float* __restrict__ cb){
    __shared__ u16 As[64*32];
    __shared__ u16 Bs[64*32];
    __shared__ u16 sXC[67*32];
    int tid = threadIdx.x;
    int wave = tid >> 6, lane = tid & 63;
    XCD_SWZ(bx, by);
    int bm = by*64;
    int kbase = bx*128;                    // 4 ksteps of 32
    int b0row = (bm/L_)*L_;
    int wr = (wave>>2)*32, wc = (wave&3)*16;
    f32x4 acc[2] = {};
    int lrow = lane & 15, lk = (lane>>4)*8;
    int w4 = wave & 3;
    int dphys = w4*1024 + lane*16;
    int alog  = dphys ^ (((dphys>>7)&7)<<4);
    int grow  = alog >> 6;
    int gcol  = (alog & 63) >> 1;
    const u16* Br = Bw + (size_t)grow*DI_ + gcol;    // N=64 rows, bn=0
    int aoff[2], boff;
    #pragma unroll
    for (int f=0; f<2; ++f){
        int ra = wr + f*16 + lrow;
        aoff[f] = (ra*64 + lk*2) ^ (((ra>>1)&7)<<4);
    }
    { int rb = wc + lrow; boff = (rb*64 + lk*2) ^ (((rb>>1)&7)<<4); }
    for (int t = 0; t < 4; ++t){
        int k0 = kbase + t*32;
        if (wave >= 4) gload_lds16(Br + k0, &Bs[w4*512]);
        if (tid < 268){
            int rr = tid >> 2, c16 = (tid & 3)*8;
            int gr = bm + rr - 3;
            uint4 v = make_uint4(0,0,0,0);
            if (gr >= b0row) v = *(const uint4*)&xzb[(size_t)gr*2048 + k0 + c16];
            *(uint4*)&sXC[rr*32 + c16] = v;
        }
        __syncthreads();
        {
            int o = tid*4, rr = o >> 5, cc0 = o & 31;
            union { u16 us[4]; uint2 q; } w;
            #pragma unroll
            for (int j=0;j<4;++j){
                int cc = cc0 + j, d = k0 + cc;
                float4 wv = *(const float4*)&cw[d*4];
                float a = cb[d];
                a = fmaf(b2f(sXC[(rr+0)*32+cc]), wv.x, a);
                a = fmaf(b2f(sXC[(rr+1)*32+cc]), wv.y, a);
                a = fmaf(b2f(sXC[(rr+2)*32+cc]), wv.z, a);
                a = fmaf(b2f(sXC[(rr+3)*32+cc]), wv.w, a);
                w.us[j] = f2b(siluf_(a));
            }
            int L0 = rr*64 + cc0*2;
            int ph = L0 ^ (((L0>>7)&7)<<4);
            *(uint2*)((char*)As + ph) = w.q;
        }
        __syncthreads();
        bf16x8 af[2], bfr;
        #pragma unroll
        for (int f=0; f<2; ++f) af[f] = *(const bf16x8*)((const char*)As + aoff[f]);
        bfr = *(const bf16x8*)((const char*)Bs + boff);
        #pragma unroll
        for (int fm=0; fm<2; ++fm)
            acc[fm] = __builtin_amdgcn_mfma_f32_16x16x32_bf16(af[fm], bfr, acc[fm], 0,0,0);
        __syncthreads();
    }
    // atomic accumulate partial tile directly into xdbl (zeroed by k_init)
    #pragma unroll
    for (int fm=0; fm<2; ++fm){
        int m0 = bm + wr + fm*16 + (lane>>4)*4;
        int n = wc + (lane&15);
        #pragma unroll
        for (int j=0; j<4; ++j)
            atomicAdd(&C[(size_t)(m0+j)*64 + n], acc[fm][j]);
    }
}

// ---------------- chunked selective scan (CL=16), Δ-proj + conv fused; bf16 chunk state ----
__global__ __launch_bounds__(256) void k_scan1(const u16* __restrict__ xzb, const float* __restrict__ xdbl,
                                               const float* __restrict__ dtw, const float* __restrict__ dtb,
                                               const float* __restrict__ cw, const float* __restrict__ cb,
                                               const float* __restrict__ Alog,
                                               u16* __restrict__ hend, u16* __restrict__ P){
    __shared__ float sX[CL_*64];      // [16][64]: dt 0:32 | B 32:48 | C 48:64
    __shared__ float sW[64*33];
    __shared__ float sDtb[64];
    __shared__ float sDel[CL_*64];
    __shared__ float sU[CL_*64];
    __shared__ u16   sXC[19*64];
    int blk = blockIdx.x;             // B*NC*16 = 2560
    int dgrp = blk & 15;
    int c = (blk>>4) % NC_;
    int b = blk/(16*NC_);
    int d0 = dgrp*64;
    int tid = threadIdx.x;
    size_t rowbase = (size_t)(b*L_ + c*CL_);
    {
        int e = tid*4;
        *(float4*)&sX[e] = *(const float4*)&xdbl[rowbase*64 + e];
        int w0 = tid*8, dr = w0>>5, kk = w0&31;
        float4 wa = *(const float4*)&dtw[(size_t)(d0+dr)*DTR_ + kk];
        float4 wb = *(const float4*)&dtw[(size_t)(d0+dr)*DTR_ + kk + 4];
        sW[dr*33+kk+0]=wa.x; sW[dr*33+kk+1]=wa.y; sW[dr*33+kk+2]=wa.z; sW[dr*33+kk+3]=wa.w;
        sW[dr*33+kk+4]=wb.x; sW[dr*33+kk+5]=wb.y; sW[dr*33+kk+6]=wb.z; sW[dr*33+kk+7]=wb.w;
        if (tid < 64) sDtb[tid] = dtb[d0+tid];
    }
    if (tid < 152){                    // 19 rows x 8 uint4
        int rr = tid >> 3, c8 = (tid & 7)*8;
        long gr = (long)rowbase + rr - 3;
        uint4 v = make_uint4(0,0,0,0);
        if (gr >= (long)b*L_) v = *(const uint4*)&xzb[(size_t)gr*2048 + d0 + c8];
        *(uint4*)&sXC[rr*64 + c8] = v;
    }
    __syncthreads();
    {
        int o = tid*4, t = o>>6, dd0 = o&63;
        #pragma unroll
        for (int j=0;j<4;++j){
            int dd = dd0 + j, d = d0 + dd;
            float4 wv = *(const float4*)&cw[d*4];
            float a = cb[d];
            a = fmaf(b2f(sXC[(t+0)*64+dd]), wv.x, a);
            a = fmaf(b2f(sXC[(t+1)*64+dd]), wv.y, a);
            a = fmaf(b2f(sXC[(t+2)*64+dd]), wv.z, a);
            a = fmaf(b2f(sXC[(t+3)*64+dd]), wv.w, a);
            sU[t*64+dd] = siluf_(a);
        }
    }
    #pragma unroll
    for (int i=0;i<4;++i){
        int idx = tid + i*256;
        int t = idx>>6, dd = idx&63;
        float acc = sDtb[dd];
        #pragma unroll
        for (int k=0;k<DTR_;++k) acc = fmaf(sX[t*64+k], sW[dd*33+k], acc);
        sDel[idx] = softplusf_(acc);
    }
    __syncthreads();
    int dl = tid>>2, sg = (tid&3)*4;
    int d = d0 + dl;
    float A[4];
    #pragma unroll
    for (int i=0;i<4;++i) A[i] = -__expf(Alog[d*DS_ + sg + i]);
    float h[4] = {0,0,0,0}, Pl[4] = {1.f,1.f,1.f,1.f};
    #pragma unroll
    for (int t=0;t<CL_;++t){
        float delta = sDel[t*64+dl];
        float du    = delta*sU[t*64+dl];
        #pragma unroll
        for (int i=0;i<4;++i){
            float a = __expf(delta*A[i]);
            h[i]  = fmaf(a, h[i], du*sX[t*64 + 32 + sg + i]);
            Pl[i] *= a;
        }
    }
    size_t ob = ((size_t)((b*NC_+c)*DI_) + d)*DS_ + sg;   // multiple of 4 -> uint2 aligned
    union { u16 us[4]; uint2 q; } oh, op;
    #pragma unroll
    for (int i=0;i<4;++i){ oh.us[i]=f2b(h[i]); op.us[i]=f2b(Pl[i]); }
    *(uint2*)&hend[ob] = oh.q;
    *(uint2*)&P[ob]    = op.q;
}

// pass 2: sequential combine across chunks (8-deep load pipelining); hstart in-place into hend (bf16)
__global__ __launch_bounds__(256) void k_scan2(u16* __restrict__ hend, const u16* __restrict__ P){
    int g = blockIdx.x*256 + threadIdx.x;        // B*DI*DS = 32768
    int s = g & 15;
    int d = (g>>4) & 1023;
    int b = g>>14;
    size_t base = ((size_t)b*NC_*DI_ + d)*DS_ + s;
    const size_t cs = (size_t)DI_*DS_;
    float h = 0.f;
    for (int c0=0;c0<NC_;c0+=8){
        float he[8], p[8];
        #pragma unroll
        for (int j=0;j<8;++j){ size_t idx = base + (size_t)(c0+j)*cs; he[j]=b2f(hend[idx]); p[j]=b2f(P[idx]); }
        #pragma unroll
        for (int j=0;j<8;++j){ size_t idx = base + (size_t)(c0+j)*cs; hend[idx]=f2b(h); h=fmaf(p[j],h,he[j]); }
    }
}

// pass 3: rerun chunk with correct initial state; conv + Δ fused; gate; emit bf16 y
__global__ __launch_bounds__(256) void k_scan3(const u16* __restrict__ xzb, const float* __restrict__ xdbl,
                                               const float* __restrict__ dtw, const float* __restrict__ dtb,
                                               const float* __restrict__ cw, const float* __restrict__ cb,
                                               const float* __restrict__ Alog, const float* __restrict__ Dsk,
                                               const u16* __restrict__ hstart, u16* __restrict__ yb){
    __shared__ float sX[CL_*64];
    __shared__ float sW[64*33];
    __shared__ float sDtb[64];
    __shared__ float sDel[CL_*64];
    __shared__ float sU[CL_*64];
    __shared__ float sY[CL_*64];
    __shared__ u16   sXC[19*64];
    int blk = blockIdx.x;
    int dgrp = blk & 15;
    int c = (blk>>4) % NC_;
    int b = blk/(16*NC_);
    int d0 = dgrp*64;
    int tid = threadIdx.x;
    size_t rowbase = (size_t)(b*L_ + c*CL_);
    {
        int e = tid*4;
        *(float4*)&sX[e] = *(const float4*)&xdbl[rowbase*64 + e];
        int w0 = tid*8, dr = w0>>5, kk = w0&31;
        float4 wa = *(const float4*)&dtw[(size_t)(d0+dr)*DTR_ + kk];
        float4 wb = *(const float4*)&dtw[(size_t)(d0+dr)*DTR_ + kk + 4];
        sW[dr*33+kk+0]=wa.x; sW[dr*33+kk+1]=wa.y; sW[dr*33+kk+2]=wa.z; sW[dr*33+kk+3]=wa.w;
        sW[dr*33+kk+4]=wb.x; sW[dr*33+kk+5]=wb.y; sW[dr*33+kk+6]=wb.z; sW[dr*33+kk+7]=wb.w;
        if (tid < 64) sDtb[tid] = dtb[d0+tid];
    }
    if (tid < 152){
        int rr = tid >> 3, c8 = (tid & 7)*8;
        long gr = (long)rowbase + rr - 3;
        uint4 v = make_uint4(0,0,0,0);
        if (gr >= (long)b*L_) v = *(const uint4*)&xzb[(size_t)gr*2048 + d0 + c8];
        *(uint4*)&sXC[rr*64 + c8] = v;
    }
    __syncthreads();
    {
        int o = tid*4, t = o>>6, dd0 = o&63;
        #pragma unroll
        for (int j=0;j<4;++j){
            int dd = dd0 + j, d = d0 + dd;
            float4 wv = *(const float4*)&cw[d*4];
            float a = cb[d];
            a = fmaf(b2f(sXC[(t+0)*64+dd]), wv.x, a);
            a = fmaf(b2f(sXC[(t+1)*64+dd]), wv.y, a);
            a = fmaf(b2f(sXC[(t+2)*64+dd]), wv.z, a);
            a = fmaf(b2f(sXC[(t+3)*64+dd]), wv.w, a);
            sU[t*64+dd] = siluf_(a);
        }
    }
    #pragma unroll
    for (int i=0;i<4;++i){
        int idx = tid + i*256;
        int t = idx>>6, dd = idx&63;
        float acc = sDtb[dd];
        #pragma unroll
        for (int k=0;k<DTR_;++k) acc = fmaf(sX[t*64+k], sW[dd*33+k], acc);
        sDel[idx] = softplusf_(acc);
    }
    __syncthreads();
    int dl = tid>>2, sg = (tid&3)*4;
    int d = d0 + dl;
    float A[4];
    #pragma unroll
    for (int i=0;i<4;++i) A[i] = -__expf(Alog[d*DS_ + sg + i]);
    size_t ib = ((size_t)((b*NC_+c)*DI_) + d)*DS_ + sg;
    uint2 hq = *(const uint2*)&hstart[ib];
    float h[4] = { b2f((u16)(hq.x&0xffffu)), b2f((u16)(hq.x>>16)),
                   b2f((u16)(hq.y&0xffffu)), b2f((u16)(hq.y>>16)) };
    #pragma unroll
    for (int t=0;t<CL_;++t){
        float delta = sDel[t*64+dl];
        float du    = delta*sU[t*64+dl];
        float yt = 0.f;
        #pragma unroll
        for (int i=0;i<4;++i){
            float a = __expf(delta*A[i]);
            h[i] = fmaf(a, h[i], du*sX[t*64 + 32 + sg + i]);
            yt   = fmaf(h[i], sX[t*64 + 48 + sg + i], yt);
        }
        yt += __shfl_xor(yt, 1);
        yt += __shfl_xor(yt, 2);
        if ((tid&3)==0) sY[t*64+dl] = yt;
    }
    __syncthreads();
    {
        int e = tid*4, st = e>>6, dd = e&63;
        size_t off = (rowbase+st)*DI_ + d0 + dd;
        float4 dskv = *(const float4*)&Dsk[d0+dd];
        uint2 zz = *(const uint2*)&xzb[(rowbase+st)*2048 + DI_ + d0 + dd];
        float z0 = __uint_as_float(zz.x<<16),  z1 = __uint_as_float(zz.x & 0xffff0000u);
        float z2 = __uint_as_float(zz.y<<16),  z3 = __uint_as_float(zz.y & 0xffff0000u);
        union { u16 us[4]; uint2 q; } o;
        o.us[0] = f2b((sY[e+0] + sU[e+0]*dskv.x) * siluf_(z0));
        o.us[1] = f2b((sY[e+1] + sU[e+1]*dskv.y) * siluf_(z1));
        o.us[2] = f2b((sY[e+2] + sU[e+2]*dskv.z) * siluf_(z2));
        o.us[3] = f2b((sY[e+3] + sU[e+3]*dskv.w) * siluf_(z3));
        *(uint2*)&yb[off] = o.q;
    }
}

// ---------------- fused LayerNorm + final projection (BK=128 GEMM phase) ----------------
__global__ __launch_bounds__(512) void k_lnmm(const float* __restrict__ x, const float* __restrict__ g_,
                                              const float* __restrict__ be_,
                                              const u16* __restrict__ Bw,
                                              const float* __restrict__ bias, float* __restrict__ out){
    __shared__ u16 ALn[64*512];       // 64 KB
    __shared__ u16 Bs[2][64*128];     // 2 x 16 KB
    int tid = threadIdx.x;
    int wave = tid >> 6, lane = tid & 63;
    int bm = blockIdx.y*64, bn = blockIdx.x*64;
    for (int rr8 = 0; rr8 < 8; ++rr8){
        int rr = wave*8 + rr8;
        int tr = bm + rr;
        int xrow = (tr>>8)*L_ + CTX_ + (tr&255);
        const float* row = x + (size_t)xrow*DM_ + lane*8;
        float4 a = *(const float4*)row;
        float4 b = *(const float4*)(row+4);
        float s  = a.x+a.y+a.z+a.w + b.x+b.y+b.z+b.w;
        float sq = a.x*a.x+a.y*a.y+a.z*a.z+a.w*a.w + b.x*b.x+b.y*b.y+b.z*b.z+b.w*b.w;
        #pragma unroll
        for (int off=32; off; off>>=1){ s += __shfl_xor(s,off); sq += __shfl_xor(sq,off); }
        float mu = s*(1.f/DM_);
        float rs = rsqrtf(sq*(1.f/DM_) - mu*mu + 1e-5f);
        int c0 = lane*8;
        float4 g0 = *(const float4*)&g_[c0],  g1 = *(const float4*)&g_[c0+4];
        float4 b0 = *(const float4*)&be_[c0], b1 = *(const float4*)&be_[c0+4];
        union { u16 us[8]; uint4 v; } o;
        o.us[0]=f2b((a.x-mu)*rs*g0.x+b0.x); o.us[1]=f2b((a.y-mu)*rs*g0.y+b0.y);
        o.us[2]=f2b((a.z-mu)*rs*g0.z+b0.z); o.us[3]=f2b((a.w-mu)*rs*g0.w+b0.w);
        o.us[4]=f2b((b.x-mu)*rs*g1.x+b1.x); o.us[5]=f2b((b.y-mu)*rs*g1.y+b1.y);
        o.us[6]=f2b((b.z-mu)*rs*g1.z+b1.z); o.us[7]=f2b((b.w-mu)*rs*g1.w+b1.w);
        int ph = (rr*1024) + ((lane*16) ^ ((rr&7)<<4));
        *(uint4*)((char*)ALn + ph) = o.v;
    }
    __syncthreads();
    int wr = (wave>>2)*32, wc = (wave&3)*16;
    f32x4 acc[2] = {};
    int lrow = lane & 15, lk = (lane>>4)*8;
    int w4 = wave & 3;
    const u16* Sr[4];
    int dstoff[4];
    #pragma unroll
    for (int i=0;i<4;++i){
        int dphys = i*4096 + w4*1024 + lane*16;
        int alog  = dphys ^ (((dphys>>8)&7)<<4);
        int grow  = alog >> 8;
        int gcol  = (alog & 255) >> 1;
        Sr[i] = Bw + (size_t)(bn+grow)*DM_ + gcol;
        dstoff[i] = i*2048 + w4*512;
    }
    int boff4[4];
    { int rb = wc + lrow;
      #pragma unroll
      for (int s=0;s<4;++s) boff4[s] = (rb*256 + s*64 + lk*2) ^ ((rb&7)<<4); }
    int ra0 = wr + lrow, ra1 = wr + 16 + lrow;
    auto stage = [&](int t, int buf){
        if (wave >= 4){
            int k0 = t*128;
            #pragma unroll
            for (int i=0;i<4;++i) gload_lds16(Sr[i] + k0, &Bs[buf][0] + dstoff[i]);
        }
    };
    stage(0, 0);
    PIPE_SYNC;
    int cur = 0;
    for (int t = 0; t < 4; ++t){      // K=512 / 128
        if (t+1 < 4) stage(t+1, cur^1);
        #pragma unroll
        for (int s=0;s<4;++s){
            int kb = (t*128 + s*32 + lk)*2;
            bf16x8 af0 = *(const bf16x8*)((const char*)ALn + (ra0*1024 + (kb ^ ((ra0&7)<<4))));
            bf16x8 af1 = *(const bf16x8*)((const char*)ALn + (ra1*1024 + (kb ^ ((ra1&7)<<4))));
            bf16x8 bfr = *(const bf16x8*)((const char*)Bs[cur] + boff4[s]);
            acc[0] = __builtin_amdgcn_mfma_f32_16x16x32_bf16(af0, bfr, acc[0], 0,0,0);
            acc[1] = __builtin_amdgcn_mfma_f32_16x16x32_bf16(af1, bfr, acc[1], 0,0,0);
        }
        PIPE_SYNC;
        cur ^= 1;
    }
    #pragma unroll
    for (int fm=0; fm<2; ++fm){
        int m0 = bm + wr + fm*16 + (lane>>4)*4;
        int n = bn + wc + (lane&15);
        float bsv = bias[n];
        #pragma unroll
        for (int j=0; j<4; ++j)
            out[(size_t)(m0+j)*DM_ + n] = acc[fm][j] + bsv;
    }
}

// ---------------- host launch ----------------
extern "C" void kernel_launch(void* const* d_in, const int* in_sizes, int n_in,
                              void* d_out, int out_size, void* d_ws, size_t ws_size,
                              hipStream_t stream) {
    const float* ctx    = (const float*)d_in[0];
    const float* te     = (const float*)d_in[1];
    const float* ve     = (const float*)d_in[2];
    const float* pos_w  = (const float*)d_in[4];
    const float* pos_b  = (const float*)d_in[5];
    const float* outp_w = (const float*)d_in[6];
    const float* outp_b = (const float*)d_in[7];
    const float* ln_g   = (const float*)d_in[8];
    const float* ln_b   = (const float*)d_in[9];
    const float* in_w   = (const float*)d_in[10];
    const float* conv_w = (const float*)d_in[11];
    const float* conv_b = (const float*)d_in[12];
    const float* xproj_w= (const float*)d_in[13];
    const float* dt_w   = (const float*)d_in[14];
    const float* dt_b   = (const float*)d_in[15];
    const float* A_log  = (const float*)d_in[16];
    const float* D_skip = (const float*)d_in[17];
    const float* out_w  = (const float*)d_in[18];
    float* out = (float*)d_out;

    float* ws    = (float*)d_ws;
    float* x     = ws;                       // 1,310,720 fp32
    float* xdbl0 = x     + 1310720;          //   163,840 fp32
    float* xdbl1 = xdbl0 + 163840;           //   163,840 fp32
    u16*  hend  = (u16*)(xdbl1 + 163840);    // 2,621,440 u16 (bf16)
    u16*  P     = hend  + 2621440;           // 2,621,440
    u16*  xb    = P     + 2621440;           // 1,310,720
    u16*  tcb   = xb    + 1310720;           //   524,288
    u16*  yb    = tcb   + 524288;            // 2,621,440
    u16*  xzb   = yb    + 2621440;           // 5,242,880
    u16*  inwb  = xzb   + 5242880;           // 2,097,152
    u16*  outwb = inwb  + 2097152;           // 1,048,576
    u16*  poswb = outwb + 1048576;           //   524,288
    u16*  outpwb= poswb + 524288;            //   262,144
    u16*  xpwb  = outpwb+ 262144;            //   131,072

    k_init<<<3840, 256, 0, stream>>>(in_w, out_w, pos_w, outp_w, xproj_w,
                                     inwb, outwb, poswb, outpwb, xpwb,
                                     ctx, te, ve, x, xb, tcb, xdbl0, xdbl1);
    // pos projection, scattered directly into x/xb target rows (K=1024 -> 8 BK128 steps)
    k_mmx64<false,true><<<dim3(8,8), 512, 0, stream>>>(tcb, 2*DM_, poswb, 2*DM_, x, DM_, pos_b, 8, xb, DM_);

    for (int i=0;i<NL_;++i){
        const u16*   inwbi  = inwb + (size_t)i*2*DI_*DM_;
        const float* cw     = conv_w  + (size_t)i*DI_*DCONV_;
        const float* cb     = conv_b  + (size_t)i*DI_;
        const u16*   xpwbi  = xpwb + (size_t)i*(DTR_+2*DS_)*DI_;
        const float* dtw    = dt_w    + (size_t)i*DI_*DTR_;
        const float* dtb    = dt_b    + (size_t)i*DI_;
        const float* Ai     = A_log   + (size_t)i*DI_*DS_;
        const float* Dsk    = D_skip  + (size_t)i*DI_;
        const u16*   outwbi = outwb + (size_t)i*DM_*DI_;
        float*       xdbl   = (i == 0) ? xdbl0 : xdbl1;

        k_mmx<true><<<dim3(16,20), 512, 0, stream>>>(xb, DM_, inwbi, DM_, nullptr, 0, nullptr, DM_, xzb, 2*DI_);
        k_xproj<<<dim3(8,40), 512, 0, stream>>>(xzb, xpwbi, xdbl, cw, cb);
        k_scan1<<<2560, 256, 0, stream>>>(xzb, xdbl, dtw, dtb, cw, cb, Ai, hend, P);
        k_scan2<<<128, 256, 0, stream>>>(hend, P);
        k_scan3<<<2560, 256, 0, stream>>>(xzb, xdbl, dtw, dtb, cw, cb, Ai, Dsk, hend, yb);
        // out-proj: K=1024 -> 8 BK128 steps
        k_mmx64<true,false><<<dim3(8,40), 512, 0, stream>>>(yb, DI_, outwbi, DI_, x, DM_, nullptr, 8, xb, DM_);
    }

    k_lnmm<<<dim3(8,8), 512, 0, stream>>>(x, ln_g, ln_b, outpwb, outp_b, out);
}